// Round 4
// baseline (417.867 us; speedup 1.0000x reference)
//
#include <hip/hip_runtime.h>
#include <cstdint>
#include <cstddef>

// Problem constants: B=64, N=1024, D=512, C=512, K=16, GAMMA=0.3, TEMP=0.07
#define INV_TEMP 14.285714285714285714f
#define GAMMA_ 0.3f

// Old path rows: 0..65535 = vpat; 65536..65599 = cls; 65600..65663 = pad.
#define ROWS_PAD 65664
// New path rows padded to 257*256: 0..65535 vpat; 65536..65599 cls; rest pad.
#define ROWS_NEW 65792

typedef short short8 __attribute__((ext_vector_type(8)));
typedef float floatx4 __attribute__((ext_vector_type(4)));

#if __has_builtin(__builtin_amdgcn_fmed3f)
#define MED3(v, hi, lo) __builtin_amdgcn_fmed3f((v), (hi), (lo))
#else
#define MED3(v, hi, lo) fmaxf(fminf((v), (hi)), (lo))
#endif

__device__ __forceinline__ unsigned short f2bf(float x) {
  unsigned int u = __float_as_uint(x);
  u += 0x7FFFu + ((u >> 16) & 1u);  // round-to-nearest-even
  return (unsigned short)(u >> 16);
}
__device__ __forceinline__ float bf2f(unsigned short h) {
  return __uint_as_float(((unsigned int)h) << 16);
}

// Branchless sorted-descending top-16 insert: 15 med3 + 1 max.
__device__ __forceinline__ void insert16(float (&top)[16], float v) {
#pragma unroll
  for (int j = 15; j >= 1; --j) top[j] = MED3(v, top[j - 1], top[j]);
  top[0] = fmaxf(top[0], v);
}

#define GL16(srcp, dstp)                                                        \
  __builtin_amdgcn_global_load_lds(                                             \
      (const __attribute__((address_space(1))) void*)(srcp),                    \
      (__attribute__((address_space(3))) void*)(dstp), 16, 0, 0)

// ===========================================================================
// NEW PATH
// ===========================================================================

// pack v2: 4 rows per wave (8 loads in flight, 4 independent reduce chains).
// Unified row space: 0..511 text -> Bh/Bl; 512.. -> A row r-512 (vpat <
// 65536, cls < 65600, zeros to 65792). Boundaries all multiples of 4.
// Numerics: fp32 l2norm, RNE bf16 hi, exact residual lo.
__global__ __launch_bounds__(256) void pack_kernel(
    const float* __restrict__ vcls, const float* __restrict__ vpat,
    const float* __restrict__ text,
    unsigned short* __restrict__ Bh, unsigned short* __restrict__ Bl,
    unsigned short* __restrict__ Ah, unsigned short* __restrict__ Al) {
  const int g = blockIdx.x * 4 + (threadIdx.x >> 6);  // wave id 0..16575
  const int lane = threadIdx.x & 63;
  const int r0 = g * 4;  // first unified row of this wave's group

  const float* src = nullptr;
  size_t srow = 0;
  unsigned short *dh, *dl;
  bool iszero = false;
  if (r0 < 512) {
    src = text;
    srow = (size_t)r0;
    dh = Bh + (size_t)r0 * 512;
    dl = Bl + (size_t)r0 * 512;
  } else {
    const int r = r0 - 512;  // 0..65788
    dh = Ah + (size_t)r * 512;
    dl = Al + (size_t)r * 512;
    if (r < 65536) {
      src = vpat;
      srow = (size_t)r;
    } else if (r < 65600) {
      src = vcls;
      srow = (size_t)(r - 65536);
    } else {
      iszero = true;
    }
  }

  float4 v[4][2];
  if (iszero) {
    const float4 z = make_float4(0.f, 0.f, 0.f, 0.f);
#pragma unroll
    for (int q = 0; q < 4; ++q) { v[q][0] = z; v[q][1] = z; }
  } else {
#pragma unroll
    for (int q = 0; q < 4; ++q) {
      const float4* s4 = (const float4*)(src + (srow + q) * 512);
      v[q][0] = s4[lane];
      v[q][1] = s4[lane + 64];
    }
  }

  float ss[4];
#pragma unroll
  for (int q = 0; q < 4; ++q) {
    const float4 a = v[q][0], b = v[q][1];
    ss[q] = a.x * a.x + a.y * a.y + a.z * a.z + a.w * a.w +
            b.x * b.x + b.y * b.y + b.z * b.z + b.w * b.w;
  }
#pragma unroll
  for (int off = 32; off; off >>= 1) {
#pragma unroll
    for (int q = 0; q < 4; ++q) ss[q] += __shfl_xor(ss[q], off);
  }

#pragma unroll
  for (int q = 0; q < 4; ++q) {
    const float scale = 1.0f / fmaxf(sqrtf(ss[q]), 1e-12f);
    const float a[8] = {v[q][0].x * scale, v[q][0].y * scale,
                        v[q][0].z * scale, v[q][0].w * scale,
                        v[q][1].x * scale, v[q][1].y * scale,
                        v[q][1].z * scale, v[q][1].w * scale};
    ushort4 h0, l0, h1, l1;
    h0.x = f2bf(a[0]); l0.x = f2bf(a[0] - bf2f(h0.x));
    h0.y = f2bf(a[1]); l0.y = f2bf(a[1] - bf2f(h0.y));
    h0.z = f2bf(a[2]); l0.z = f2bf(a[2] - bf2f(h0.z));
    h0.w = f2bf(a[3]); l0.w = f2bf(a[3] - bf2f(h0.w));
    h1.x = f2bf(a[4]); l1.x = f2bf(a[4] - bf2f(h1.x));
    h1.y = f2bf(a[5]); l1.y = f2bf(a[5] - bf2f(h1.y));
    h1.z = f2bf(a[6]); l1.z = f2bf(a[6] - bf2f(h1.z));
    h1.w = f2bf(a[7]); l1.w = f2bf(a[7] - bf2f(h1.w));
    unsigned short* dhq = dh + (size_t)q * 512;
    unsigned short* dlq = dl + (size_t)q * 512;
    ((ushort4*)dhq)[lane] = h0;
    ((ushort4*)dhq)[lane + 64] = h1;
    ((ushort4*)dlq)[lane] = l0;
    ((ushort4*)dlq)[lane + 64] = l1;
  }
}

// gemm v3: 256x128 tile, 8 waves (512 thr, 4 wm x 2 wn), single-buffer
// 2-barrier K-loop (r1's proven structure; r3's dbuf regressed occupancy).
// Logical K' = 1536 as 24 K-tiles of 64:
//   tiles 0..7: Ah.Bh | 8..15: Al.Bh | 16..23: Ah.Bl
// Per barrier-pair: 256 MFMA (2x r1's 128) -> barrier/drain amortized 2x;
// staged bytes/output 1.5 B (vs 2 B). LDS 48 KB single buffer: sA [256][64]
// + sB [128][64] bf16, chunk-XOR swizzle (pos = g ^ (row&7)) on stage source
// and fragment reads (verified 0 bank conflicts in r1/r3).
__global__ __launch_bounds__(512) void gemm_lean_kernel(
    const unsigned short* __restrict__ Ah, const unsigned short* __restrict__ Al,
    const unsigned short* __restrict__ Bh, const unsigned short* __restrict__ Bl,
    float* __restrict__ Cout, float* __restrict__ pstat) {
  __shared__ __align__(16) unsigned short smem[24576];  // 48 KB
  unsigned short* sA = smem;          // [256][64] bf16 (32 KB)
  unsigned short* sB = smem + 16384;  // [128][64] bf16 (16 KB)
  const int tid = threadIdx.x;
  const int lane = tid & 63;
  const int w = tid >> 6;            // 0..7
  const int wm = w >> 1, wn = w & 1; // rows wm*64, cols wn*64

  // Bijective XCD remap, nwg = 1028 = 8*128 + 4 (m204 formula).
  const int L = blockIdx.x;  // 0..1027
  const int xcd = L & 7;     // L % 8
  const int i8 = L >> 3;     // L / 8
  const int wg = (xcd < 4 ? xcd * 129 : 4 * 129 + (xcd - 4) * 128) + i8;
  const int bn = wg & 3;     // 0..3
  const int bm = wg >> 2;    // 0..256

  // A staging: 2048 16B-slots (256 rows x 8 chunks); thread owns tid + q*512.
  // slot s -> row = s>>3, pos = s&7, source chunk g = pos ^ (row&7).
  unsigned aOff[4];
#pragma unroll
  for (int q = 0; q < 4; ++q) {
    const int s = tid + q * 512;
    const int row = s >> 3, pos = s & 7;
    const int g = pos ^ (row & 7);
    aOff[q] = (unsigned)(bm * 256 + row) * 512u + (unsigned)g * 8u;  // ushort
  }
  // B staging: 1024 slots (128 rows x 8 chunks); thread owns tid + q*512.
  unsigned bOff[2];
#pragma unroll
  for (int q = 0; q < 2; ++q) {
    const int s = tid + q * 512;
    const int row = s >> 3, pos = s & 7;
    const int g = pos ^ (row & 7);
    bOff[q] = (unsigned)(bn * 128 + row) * 512u + (unsigned)g * 8u;
  }

  const int l15 = lane & 15, kg = lane >> 4;
  // Fragment LDS offsets (ushort units): row of 64 bf16 = 8 chunks of 8;
  // k-step k2 chunk c = k2*4+kg, swizzled p = c ^ (row&7).
  int fA[4][2], fB[4][2];
#pragma unroll
  for (int i = 0; i < 4; ++i) {
    const int ml = wm * 64 + i * 16 + l15;   // 0..255
    const int nl = wn * 64 + i * 16 + l15;   // 0..127
#pragma unroll
    for (int k2 = 0; k2 < 2; ++k2) {
      const int c = k2 * 4 + kg;
      fA[i][k2] = ml * 64 + (c ^ (ml & 7)) * 8;
      fB[i][k2] = nl * 64 + (c ^ (nl & 7)) * 8;
    }
  }

  floatx4 acc[4][4] = {};

#pragma unroll 1
  for (int t = 0; t < 24; ++t) {
    const unsigned short* Asrc = ((t >> 3) == 1) ? Al : Ah;
    const unsigned short* Bsrc = ((t >> 3) == 2) ? Bl : Bh;
    const unsigned ko = (unsigned)(t & 7) * 64u;
#pragma unroll
    for (int q = 0; q < 4; ++q)
      GL16(Asrc + aOff[q] + ko, sA + (w * 512 + q * 4096));
#pragma unroll
    for (int q = 0; q < 2; ++q)
      GL16(Bsrc + bOff[q] + ko, sB + (w * 512 + q * 4096));
    __syncthreads();
#pragma unroll
    for (int k2 = 0; k2 < 2; ++k2) {
      short8 a[4], b[4];
#pragma unroll
      for (int i = 0; i < 4; ++i) a[i] = *(const short8*)(sA + fA[i][k2]);
#pragma unroll
      for (int j = 0; j < 4; ++j) b[j] = *(const short8*)(sB + fB[j][k2]);
#pragma unroll
      for (int i = 0; i < 4; ++i)
#pragma unroll
        for (int j = 0; j < 4; ++j)
          acc[i][j] = __builtin_amdgcn_mfma_f32_16x16x32_bf16(
              a[i], b[j], acc[i][j], 0, 0, 0);
    }
    __syncthreads();
  }

  // C/D layout: col=lane&15, row=(lane>>4)*4+reg  [m89/m91 verified]
  // Rows pre-normalized -> no scaling; fused partial sumexp (fixed max 1.0).
  const unsigned rowb0 = (unsigned)(bm * 256 + wm * 64 + kg * 4);
  const unsigned colb0 = (unsigned)(bn * 128 + wn * 64 + l15);
  const int pk = bn * 2 + wn;  // pstat slot 0..7 (4 bn x 2 wn)
#pragma unroll
  for (int i = 0; i < 4; ++i) {
#pragma unroll
    for (int j = 0; j < 4; ++j) {
      const unsigned col = colb0 + j * 16;
#pragma unroll
      for (int r = 0; r < 4; ++r)
        Cout[(size_t)(rowb0 + i * 16 + r) * 512 + col] = acc[i][j][r];
    }
#pragma unroll
    for (int r = 0; r < 4; ++r) {
      float se = __expf((acc[i][0][r] - 1.0f) * INV_TEMP) +
                 __expf((acc[i][1][r] - 1.0f) * INV_TEMP) +
                 __expf((acc[i][2][r] - 1.0f) * INV_TEMP) +
                 __expf((acc[i][3][r] - 1.0f) * INV_TEMP);
      se += __shfl_xor(se, 1);
      se += __shfl_xor(se, 2);
      se += __shfl_xor(se, 4);
      se += __shfl_xor(se, 8);
      if (l15 == 0) pstat[(size_t)(rowb0 + i * 16 + r) * 8 + pk] = se;
    }
  }
}

// ===========================================================================
// OLD PATH (fallback if workspace too small for packed-A buffers).
// ===========================================================================

__global__ __launch_bounds__(256) void prep_kernel(
    const float* __restrict__ vcls, const float* __restrict__ text,
    unsigned short* __restrict__ Bh, unsigned short* __restrict__ Bl,
    float* __restrict__ Aext) {
  const int wid = blockIdx.x * 4 + (threadIdx.x >> 6);
  const int lane = threadIdx.x & 63;
  if (wid < 512) {
    const float* src = text + (size_t)wid * 512;
    const float4 v0 = ((const float4*)src)[lane];
    const float4 v1 = ((const float4*)src)[lane + 64];
    float ss = v0.x * v0.x + v0.y * v0.y + v0.z * v0.z + v0.w * v0.w +
               v1.x * v1.x + v1.y * v1.y + v1.z * v1.z + v1.w * v1.w;
#pragma unroll
    for (int off = 32; off; off >>= 1) ss += __shfl_xor(ss, off);
    const float scale = 1.0f / fmaxf(sqrtf(ss), 1e-12f);
    float a[8] = {v0.x * scale, v0.y * scale, v0.z * scale, v0.w * scale,
                  v1.x * scale, v1.y * scale, v1.z * scale, v1.w * scale};
    ushort4 h0, l0, h1, l1;
    h0.x = f2bf(a[0]); l0.x = f2bf(a[0] - bf2f(h0.x));
    h0.y = f2bf(a[1]); l0.y = f2bf(a[1] - bf2f(h0.y));
    h0.z = f2bf(a[2]); l0.z = f2bf(a[2] - bf2f(h0.z));
    h0.w = f2bf(a[3]); l0.w = f2bf(a[3] - bf2f(h0.w));
    h1.x = f2bf(a[4]); l1.x = f2bf(a[4] - bf2f(h1.x));
    h1.y = f2bf(a[5]); l1.y = f2bf(a[5] - bf2f(h1.y));
    h1.z = f2bf(a[6]); l1.z = f2bf(a[6] - bf2f(h1.z));
    h1.w = f2bf(a[7]); l1.w = f2bf(a[7] - bf2f(h1.w));
    ((ushort4*)(Bh + (size_t)wid * 512))[lane] = h0;
    ((ushort4*)(Bh + (size_t)wid * 512))[lane + 64] = h1;
    ((ushort4*)(Bl + (size_t)wid * 512))[lane] = l0;
    ((ushort4*)(Bl + (size_t)wid * 512))[lane + 64] = l1;
  } else {
    const int r = wid - 512;  // 0..127
    float4* dst = (float4*)(Aext + (size_t)r * 512);
    if (r < 64) {
      const float4* src = (const float4*)(vcls + (size_t)r * 512);
      dst[lane] = src[lane];
      dst[lane + 64] = src[lane + 64];
    } else {
      const float4 z = {0.f, 0.f, 0.f, 0.f};
      dst[lane] = z;
      dst[lane + 64] = z;
    }
  }
}

__global__ __launch_bounds__(256) void gemm_raw_kernel(
    const float* __restrict__ Apat, const float* __restrict__ Aext,
    const unsigned short* __restrict__ Bhi, const unsigned short* __restrict__ Blo,
    float* __restrict__ Cout, float* __restrict__ pstat) {
  __shared__ __align__(16) unsigned char smem[32768];
  float* sA = (float*)smem;                              // 128 x 32 fp32
  unsigned short* sBh = (unsigned short*)(smem + 16384); // 128 x 32 bf16
  unsigned short* sBl = (unsigned short*)(smem + 24576);
  const int tid = threadIdx.x;
  const int lane = tid & 63;
  const int w = tid >> 6;
  const int wm = w >> 1, wn = w & 1;

  const int L = blockIdx.x;  // 0..2051
  int bm, bn;
  if (L < 2048) {
    const int xcd = L & 7;
    const int slot = L >> 3;
    bn = slot & 3;
    bm = (slot >> 2) * 8 + xcd;
  } else {
    bm = 512;
    bn = L - 2048;
  }
  const float* Abase =
      (bm < 512) ? (Apat + (size_t)bm * 128 * 512) : Aext;

  unsigned aSrc[4];
#pragma unroll
  for (int q = 0; q < 4; ++q) {
    const int s = tid + q * 256;
    const int row = s >> 3, pos = s & 7;
    const int g = pos ^ (row & 7);
    aSrc[q] = (unsigned)row * 512u + (unsigned)g * 4u;
  }
  const int m0 = tid >> 2, g0 = (tid & 3) ^ ((m0 >> 1) & 3);
  const int i1 = 256 + tid;
  const int m1 = i1 >> 2, g1 = (i1 & 3) ^ ((m1 >> 1) & 3);
  const unsigned bO0 = (unsigned)(bn * 128 + m0) * 512u + (unsigned)g0 * 8u;
  const unsigned bO1 = (unsigned)(bn * 128 + m1) * 512u + (unsigned)g1 * 8u;

  const int l15 = lane & 15, kg = lane >> 4;
  int fA0[4], fA1[4], cB[4];
#pragma unroll
  for (int i = 0; i < 4; ++i) {
    const int ml = wm * 64 + i * 16 + l15;
    const int p0 = (2 * kg) ^ (ml & 7);
    const int p1 = (2 * kg + 1) ^ (ml & 7);
    fA0[i] = (ml * 8 + p0) * 4;
    fA1[i] = (ml * 8 + p1) * 4;
    const int nl = wn * 64 + i * 16 + l15;
    cB[i] = (nl * 4 + (kg ^ ((nl >> 1) & 3))) * 8;
  }

  floatx4 acc[4][4] = {};
  float ssq[4] = {0.f, 0.f, 0.f, 0.f};

  for (int ks = 0; ks < 16; ++ks) {
    const unsigned ko = (unsigned)ks * 32u;
#pragma unroll
    for (int q = 0; q < 4; ++q)
      GL16(Abase + aSrc[q] + ko, (unsigned short*)sA + (w * 512 + q * 2048));
    GL16(Bhi + bO0 + ko, sBh + (unsigned)tid * 8u);
    GL16(Bhi + bO1 + ko, sBh + 2048u + (unsigned)tid * 8u);
    GL16(Blo + bO0 + ko, sBl + (unsigned)tid * 8u);
    GL16(Blo + bO1 + ko, sBl + 2048u + (unsigned)tid * 8u);
    __syncthreads();

    short8 bh[4], bl[4];
#pragma unroll
    for (int j = 0; j < 4; ++j) {
      bh[j] = *(const short8*)(sBh + cB[j]);
      bl[j] = *(const short8*)(sBl + cB[j]);
    }
#pragma unroll
    for (int i = 0; i < 4; ++i) {
      const float4 x0 = *(const float4*)(sA + fA0[i]);
      const float4 x1 = *(const float4*)(sA + fA1[i]);
      const float xs[8] = {x0.x, x0.y, x0.z, x0.w, x1.x, x1.y, x1.z, x1.w};
      short8 ah, al;
#pragma unroll
      for (int e = 0; e < 8; ++e) {
        const float f = xs[e];
        ssq[i] = fmaf(f, f, ssq[i]);
        const unsigned u = __float_as_uint(f) + 0x8000u;
        ah[e] = (short)(u >> 16);
        const float hif = __uint_as_float(u & 0xFFFF0000u);
        al[e] = (short)(__float_as_uint(f - hif) >> 16);
      }
#pragma unroll
      for (int j = 0; j < 4; ++j) {
        acc[i][j] = __builtin_amdgcn_mfma_f32_16x16x32_bf16(ah, bh[j], acc[i][j], 0, 0, 0);
        acc[i][j] = __builtin_amdgcn_mfma_f32_16x16x32_bf16(ah, bl[j], acc[i][j], 0, 0, 0);
        acc[i][j] = __builtin_amdgcn_mfma_f32_16x16x32_bf16(al, bh[j], acc[i][j], 0, 0, 0);
      }
    }
    __syncthreads();
  }

  float inv[4];
#pragma unroll
  for (int i = 0; i < 4; ++i) {
    float s = ssq[i];
    s += __shfl_xor(s, 16);
    s += __shfl_xor(s, 32);
    inv[i] = 1.0f / fmaxf(sqrtf(s), 1e-12f);
  }

  const int quad = kg;
  const unsigned rowb0 = (unsigned)(bm * 128 + wm * 64 + quad * 4);
  const unsigned colb0 = (unsigned)(bn * 128 + wn * 64 + l15);
  const int pk = bn * 2 + wn;
#pragma unroll
  for (int i = 0; i < 4; ++i) {
    float iv[4];
#pragma unroll
    for (int r = 0; r < 4; ++r) iv[r] = __shfl(inv[i], quad * 20 + r);
    float sc[4][4];
#pragma unroll
    for (int j = 0; j < 4; ++j)
#pragma unroll
      for (int r = 0; r < 4; ++r) sc[j][r] = acc[i][j][r] * iv[r];
#pragma unroll
    for (int j = 0; j < 4; ++j) {
      const unsigned col = colb0 + j * 16;
#pragma unroll
      for (int r = 0; r < 4; ++r)
        Cout[(size_t)(rowb0 + i * 16 + r) * 512 + col] = sc[j][r];
    }
#pragma unroll
    for (int r = 0; r < 4; ++r) {
      float se = __expf((sc[0][r] - 1.0f) * INV_TEMP) +
                 __expf((sc[1][r] - 1.0f) * INV_TEMP) +
                 __expf((sc[2][r] - 1.0f) * INV_TEMP) +
                 __expf((sc[3][r] - 1.0f) * INV_TEMP);
      se += __shfl_xor(se, 1);
      se += __shfl_xor(se, 2);
      se += __shfl_xor(se, 4);
      se += __shfl_xor(se, 8);
      if (l15 == 0) pstat[(size_t)(rowb0 + i * 16 + r) * 8 + pk] = se;
    }
  }
}

// ---------------------------------------------------------------------------
// topk_partial v2: 4 cols/thread via float4 (1 KB/wave/load-instr vs 256 B),
// 128-row n-chunks (8 chunks -> 512 blocks x 2 waves = 1024 waves TLP).
// s-domain per row: s = l*invT + LW[n], LW = -(ln(sum_k pstat) + invT).
__global__ __launch_bounds__(128) void topk_partial_kernel(
    const float* __restrict__ L, const float* __restrict__ pstat,
    float* __restrict__ cand) {
  const int b = blockIdx.x;   // 0..63
  const int nc = blockIdx.z;  // 0..7
  const int t = threadIdx.x;  // 0..127; cols t*4..t*4+3
  const size_t mb = (size_t)b * 1024 + (size_t)nc * 128;

  __shared__ float sLW[128];
  {
    const float* p = pstat + (mb + t) * 8;
    float S = 0.f;
#pragma unroll
    for (int k = 0; k < 8; ++k) S += p[k];
    sLW[t] = -(__logf(S) + INV_TEMP);
  }
  __syncthreads();

  float t0[16], t1[16], t2[16], t3[16];
#pragma unroll
  for (int j = 0; j < 16; ++j) { t0[j] = -3.0e38f; t1[j] = -3.0e38f;
                                 t2[j] = -3.0e38f; t3[j] = -3.0e38f; }
  const float4* Lp = (const float4*)(L + mb * 512) + t;  // row stride 128
#pragma unroll 1
  for (int n0 = 0; n0 < 128; n0 += 4) {
    float4 v[4];
    float lw[4];
#pragma unroll
    for (int u = 0; u < 4; ++u) {
      v[u] = Lp[(size_t)(n0 + u) * 128];
      lw[u] = sLW[n0 + u];
    }
#pragma unroll
    for (int u = 0; u < 4; ++u) {
      insert16(t0, fmaf(v[u].x, INV_TEMP, lw[u]));
      insert16(t1, fmaf(v[u].y, INV_TEMP, lw[u]));
      insert16(t2, fmaf(v[u].z, INV_TEMP, lw[u]));
      insert16(t3, fmaf(v[u].w, INV_TEMP, lw[u]));
    }
  }
  // cand[b][nc][16][512], cols t*4..+3 (float4 store per rank).
  float* o = cand + ((size_t)b * 8 + nc) * 16 * 512 + (size_t)t * 4;
#pragma unroll
  for (int j = 0; j < 16; ++j)
    *(float4*)(o + (size_t)j * 512) = make_float4(t0[j], t1[j], t2[j], t3[j]);
}

// Merge 8x16 s-candidates -> top-16 mean; fused aff_g from cls logit row.
__global__ __launch_bounds__(256) void topk_merge_kernel(
    const float* __restrict__ cand, const float* __restrict__ logits,
    const float* __restrict__ pstat, float* __restrict__ out) {
  const int gid = blockIdx.x * 256 + threadIdx.x;  // b*512 + c
  const int b = gid >> 9, c = gid & 511;
  const float* cb = cand + (size_t)b * 128 * 512 + c;
  float top[16];
#pragma unroll
  for (int t = 0; t < 16; ++t) top[t] = -3.0e38f;
#pragma unroll
  for (int kb = 0; kb < 8; ++kb) {
    float v[16];
#pragma unroll
    for (int j = 0; j < 16; ++j) v[j] = cb[(size_t)(kb * 16 + j) * 512];
#pragma unroll
    for (int j = 0; j < 16; ++j) insert16(top, v[j]);
  }
  float s = 0.f;
#pragma unroll
  for (int t = 0; t < 16; ++t) s += __expf(top[t]);
  const float* pc = pstat + ((size_t)65536 + b) * 8;
  float S = 0.f;
#pragma unroll
  for (int k = 0; k < 8; ++k) S += pc[k];
  const float lg = logits[((size_t)65536 + b) * 512 + c];
  const float ag = __expf(fmaf(lg, INV_TEMP, -(__logf(S) + INV_TEMP)));
  out[gid] = GAMMA_ * ag + (1.0f - GAMMA_) * (s * (1.0f / 16.0f));
}

// ---------------------------------------------------------------------------
extern "C" void kernel_launch(void* const* d_in, const int* in_sizes, int n_in,
                              void* d_out, int out_size, void* d_ws, size_t ws_size,
                              hipStream_t stream) {
  const float* vcls = (const float*)d_in[0];  // [64,512]
  const float* vpat = (const float*)d_in[1];  // [64,1024,512]
  const float* text = (const float*)d_in[2];  // [512,512]
  float* out = (float*)d_out;                 // [64,512]

  char* p = (char*)d_ws;
  auto carve = [&](size_t bytes) -> char* {
    char* r = p;
    p += (bytes + 255) & ~(size_t)255;
    return r;
  };

  // ---- New path (pack + 256x128 lean GEMM + float4 topk): ~290 MB ws.
  {
    float* logits = (float*)carve((size_t)ROWS_NEW * 512 * 4);
    unsigned short* Bh = (unsigned short*)carve((size_t)512 * 512 * 2);
    unsigned short* Bl = (unsigned short*)carve((size_t)512 * 512 * 2);
    float* pstat = (float*)carve((size_t)ROWS_NEW * 8 * 4);
    unsigned short* Ah = (unsigned short*)carve((size_t)ROWS_NEW * 512 * 2);
    unsigned short* Al = (unsigned short*)carve((size_t)ROWS_NEW * 512 * 2);
    float* cand = (float*)carve((size_t)64 * 8 * 16 * 512 * 4);
    if ((size_t)(p - (char*)d_ws) <= ws_size) {
      pack_kernel<<<4144, 256, 0, stream>>>(vcls, vpat, text, Bh, Bl, Ah, Al);
      gemm_lean_kernel<<<1028, 512, 0, stream>>>(Ah, Al, Bh, Bl, logits, pstat);
      topk_partial_kernel<<<dim3(64, 1, 8), 128, 0, stream>>>(logits, pstat, cand);
      topk_merge_kernel<<<128, 256, 0, stream>>>(cand, logits, pstat, out);
      return;
    }
  }

  // ---- Fallback: round-0 verified pipeline (~146 MB workspace).
  p = (char*)d_ws;
  float* logits = (float*)carve((size_t)ROWS_PAD * 512 * 4);
  unsigned short* Bh = (unsigned short*)carve((size_t)512 * 512 * 2);
  unsigned short* Bl = (unsigned short*)carve((size_t)512 * 512 * 2);
  float* pstat = (float*)carve((size_t)ROWS_PAD * 8 * 4);
  float* Aext = (float*)carve((size_t)128 * 512 * 4);
  float* cand = (float*)carve((size_t)64 * 4 * 16 * 512 * 4);
  if ((size_t)(p - (char*)d_ws) > ws_size) return;

  prep_kernel<<<160, 256, 0, stream>>>(vcls, text, Bh, Bl, Aext);
  gemm_raw_kernel<<<2052, 256, 0, stream>>>(vpat, Aext, Bh, Bl, logits, pstat);
  topk_partial_kernel<<<dim3(64, 1, 8), 128, 0, stream>>>(logits, pstat, cand);
  topk_merge_kernel<<<128, 256, 0, stream>>>(cand, logits, pstat, out);
}

// Round 5
// 385.065 us; speedup vs baseline: 1.0852x; 1.0852x over previous
//
#include <hip/hip_runtime.h>
#include <cstdint>
#include <cstddef>

// Problem constants: B=64, N=1024, D=512, C=512, K=16, GAMMA=0.3, TEMP=0.07
#define INV_TEMP 14.285714285714285714f
#define GAMMA_ 0.3f

// Old path rows: 0..65535 = vpat; 65536..65599 = cls; 65600..65663 = pad.
#define ROWS_PAD 65664
// New path rows: 0..65535 vpat; 65536..65599 cls; rest pad to 514*128.
#define ROWS_NEW 65792

typedef short short8 __attribute__((ext_vector_type(8)));
typedef float floatx4 __attribute__((ext_vector_type(4)));

#if __has_builtin(__builtin_amdgcn_fmed3f)
#define MED3(v, hi, lo) __builtin_amdgcn_fmed3f((v), (hi), (lo))
#else
#define MED3(v, hi, lo) fmaxf(fminf((v), (hi)), (lo))
#endif

__device__ __forceinline__ unsigned short f2bf(float x) {
  unsigned int u = __float_as_uint(x);
  u += 0x7FFFu + ((u >> 16) & 1u);  // round-to-nearest-even
  return (unsigned short)(u >> 16);
}
__device__ __forceinline__ float bf2f(unsigned short h) {
  return __uint_as_float(((unsigned int)h) << 16);
}

// Branchless sorted-descending top-16 insert: 15 med3 + 1 max, depth-1 ILP.
__device__ __forceinline__ void insert16(float (&top)[16], float v) {
#pragma unroll
  for (int j = 15; j >= 1; --j) top[j] = MED3(v, top[j - 1], top[j]);
  top[0] = fmaxf(top[0], v);
}

#define GL16(srcp, dstp)                                                        \
  __builtin_amdgcn_global_load_lds(                                             \
      (const __attribute__((address_space(1))) void*)(srcp),                    \
      (__attribute__((address_space(3))) void*)(dstp), 16, 0, 0)

// ===========================================================================
// NEW PATH
// ===========================================================================

// pack v3: 4 rows/wave; lane owns 8 CONTIGUOUS floats (two adjacent float4
// loads) so hi/lo outputs are single 16B short8 stores (v2 did 4x 8B stores).
// Unified row space: 0..511 text -> Bh/Bl; 512.. -> A row r-512 (vpat <
// 65536, cls < 65600, zeros to 65792). Boundaries all multiples of 4.
// Numerics: fp32 l2norm, RNE bf16 hi, exact residual lo (as r1-r4).
__global__ __launch_bounds__(256) void pack_kernel(
    const float* __restrict__ vcls, const float* __restrict__ vpat,
    const float* __restrict__ text,
    unsigned short* __restrict__ Bh, unsigned short* __restrict__ Bl,
    unsigned short* __restrict__ Ah, unsigned short* __restrict__ Al) {
  const int g = blockIdx.x * 4 + (threadIdx.x >> 6);  // wave id 0..16575
  const int lane = threadIdx.x & 63;
  const int r0 = g * 4;  // first unified row of this wave's group

  const float* src = nullptr;
  size_t srow = 0;
  unsigned short *dh, *dl;
  bool iszero = false;
  if (r0 < 512) {
    src = text;
    srow = (size_t)r0;
    dh = Bh + (size_t)r0 * 512;
    dl = Bl + (size_t)r0 * 512;
  } else {
    const int r = r0 - 512;  // 0..65788
    dh = Ah + (size_t)r * 512;
    dl = Al + (size_t)r * 512;
    if (r < 65536) {
      src = vpat;
      srow = (size_t)r;
    } else if (r < 65600) {
      src = vcls;
      srow = (size_t)(r - 65536);
    } else {
      iszero = true;
    }
  }

  float4 v[4][2];
  if (iszero) {
    const float4 z = make_float4(0.f, 0.f, 0.f, 0.f);
#pragma unroll
    for (int q = 0; q < 4; ++q) { v[q][0] = z; v[q][1] = z; }
  } else {
#pragma unroll
    for (int q = 0; q < 4; ++q) {
      const float4* s4 = (const float4*)(src + (srow + q) * 512);
      v[q][0] = s4[2 * lane];      // floats 8l..8l+3
      v[q][1] = s4[2 * lane + 1];  // floats 8l+4..8l+7
    }
  }

  float ss[4];
#pragma unroll
  for (int q = 0; q < 4; ++q) {
    const float4 a = v[q][0], b = v[q][1];
    ss[q] = a.x * a.x + a.y * a.y + a.z * a.z + a.w * a.w +
            b.x * b.x + b.y * b.y + b.z * b.z + b.w * b.w;
  }
#pragma unroll
  for (int off = 32; off; off >>= 1) {
#pragma unroll
    for (int q = 0; q < 4; ++q) ss[q] += __shfl_xor(ss[q], off);
  }

#pragma unroll
  for (int q = 0; q < 4; ++q) {
    const float scale = 1.0f / fmaxf(sqrtf(ss[q]), 1e-12f);
    const float a[8] = {v[q][0].x * scale, v[q][0].y * scale,
                        v[q][0].z * scale, v[q][0].w * scale,
                        v[q][1].x * scale, v[q][1].y * scale,
                        v[q][1].z * scale, v[q][1].w * scale};
    short8 h, l;
#pragma unroll
    for (int e = 0; e < 8; ++e) {
      const unsigned short hb = f2bf(a[e]);
      h[e] = (short)hb;
      l[e] = (short)f2bf(a[e] - bf2f(hb));
    }
    *(short8*)(dh + (size_t)q * 512 + 8 * lane) = h;  // 16B store
    *(short8*)(dl + (size_t)q * 512 + 8 * lane) = l;  // 16B store
  }
}

// Lean concatenated-K bf16 GEMM — round-1 verified config (140 us, MfmaUtil
// 31.7%, bank-conflict 0): 128x128 tile, 256 thr (2x2 waves), single 32KB
// LDS buffer, 2-barrier K-loop. Logical K' = 1536 as 24 K-tiles of 64:
//   tiles 0..7: Ah.Bh | 8..15: Al.Bh | 16..23: Ah.Bl
// (r3 dbuf and r4 256x128 both regressed; this is the measured optimum.)
// Chunk-XOR swizzle (pos = g ^ (row&7)) on stage source + fragment reads.
__global__ __launch_bounds__(256) void gemm_lean_kernel(
    const unsigned short* __restrict__ Ah, const unsigned short* __restrict__ Al,
    const unsigned short* __restrict__ Bh, const unsigned short* __restrict__ Bl,
    float* __restrict__ Cout, float* __restrict__ pstat) {
  __shared__ __align__(16) unsigned short smem[16384];  // 32 KB
  unsigned short* sA = smem;         // [128][64] bf16, chunk-swizzled (16 KB)
  unsigned short* sB = smem + 8192;  // [128][64] bf16, chunk-swizzled (16 KB)
  const int tid = threadIdx.x;
  const int lane = tid & 63;
  const int w = tid >> 6;
  const int wm = w >> 1, wn = w & 1;

  const int L = blockIdx.x;                 // 0..2055
  const int wg = (L & 7) * 257 + (L >> 3);  // bijective (2056 = 8*257)
  const int bn = wg & 3;                    // 0..3
  const int bm = wg >> 2;                   // 0..513

  // Staging: 1024 16B-slots per matrix; thread owns slots tid + q*256.
  // slot s -> row = s>>3, pos = s&7, source chunk g = pos ^ (row&7).
  unsigned aOff[4], bOff[4];
#pragma unroll
  for (int q = 0; q < 4; ++q) {
    const int s = tid + q * 256;
    const int row = s >> 3, pos = s & 7;
    const int g = pos ^ (row & 7);
    aOff[q] = (unsigned)(bm * 128 + row) * 512u + (unsigned)g * 8u;  // ushort
    bOff[q] = (unsigned)(bn * 128 + row) * 512u + (unsigned)g * 8u;
  }

  const int l15 = lane & 15, kg = lane >> 4;
  // Fragment LDS offsets (ushort units): row of 64 bf16 = 8 chunks of 8;
  // k-step k2 chunk c = k2*4+kg, swizzled p = c ^ (row&7).
  int fA[4][2], fB[4][2];
#pragma unroll
  for (int i = 0; i < 4; ++i) {
    const int ml = wm * 64 + i * 16 + l15;
    const int nl = wn * 64 + i * 16 + l15;
#pragma unroll
    for (int k2 = 0; k2 < 2; ++k2) {
      const int c = k2 * 4 + kg;
      fA[i][k2] = ml * 64 + (c ^ (ml & 7)) * 8;
      fB[i][k2] = nl * 64 + (c ^ (nl & 7)) * 8;
    }
  }

  floatx4 acc[4][4] = {};

#pragma unroll 1
  for (int seg = 0; seg < 3; ++seg) {
    const unsigned short* Asrc = (seg == 1) ? Al : Ah;
    const unsigned short* Bsrc = (seg == 2) ? Bl : Bh;
#pragma unroll 1
    for (int t8 = 0; t8 < 8; ++t8) {
      const unsigned ko = (unsigned)t8 * 64u;
#pragma unroll
      for (int q = 0; q < 4; ++q)
        GL16(Asrc + aOff[q] + ko, sA + (w * 512 + q * 2048));
#pragma unroll
      for (int q = 0; q < 4; ++q)
        GL16(Bsrc + bOff[q] + ko, sB + (w * 512 + q * 2048));
      __syncthreads();
#pragma unroll
      for (int k2 = 0; k2 < 2; ++k2) {
        short8 a[4], b[4];
#pragma unroll
        for (int i = 0; i < 4; ++i) a[i] = *(const short8*)(sA + fA[i][k2]);
#pragma unroll
        for (int j = 0; j < 4; ++j) b[j] = *(const short8*)(sB + fB[j][k2]);
#pragma unroll
        for (int i = 0; i < 4; ++i)
#pragma unroll
          for (int j = 0; j < 4; ++j)
            acc[i][j] = __builtin_amdgcn_mfma_f32_16x16x32_bf16(
                a[i], b[j], acc[i][j], 0, 0, 0);
      }
      __syncthreads();
    }
  }

  // C/D layout: col=lane&15, row=(lane>>4)*4+reg  [m89/m91 verified]
  // Rows pre-normalized -> no scaling; fused partial sumexp (fixed max 1.0).
  const unsigned rowb0 = (unsigned)(bm * 128 + wm * 64 + kg * 4);
  const unsigned colb0 = (unsigned)(bn * 128 + wn * 64 + l15);
  const int pk = bn * 2 + wn;  // pstat slot 0..7
#pragma unroll
  for (int i = 0; i < 4; ++i) {
#pragma unroll
    for (int j = 0; j < 4; ++j) {
      const unsigned col = colb0 + j * 16;
#pragma unroll
      for (int r = 0; r < 4; ++r)
        Cout[(size_t)(rowb0 + i * 16 + r) * 512 + col] = acc[i][j][r];
    }
#pragma unroll
    for (int r = 0; r < 4; ++r) {
      float se = __expf((acc[i][0][r] - 1.0f) * INV_TEMP) +
                 __expf((acc[i][1][r] - 1.0f) * INV_TEMP) +
                 __expf((acc[i][2][r] - 1.0f) * INV_TEMP) +
                 __expf((acc[i][3][r] - 1.0f) * INV_TEMP);
      se += __shfl_xor(se, 1);
      se += __shfl_xor(se, 2);
      se += __shfl_xor(se, 4);
      se += __shfl_xor(se, 8);
      if (l15 == 0) pstat[(size_t)(rowb0 + i * 16 + r) * 8 + pk] = se;
    }
  }
}

// ===========================================================================
// Fused top-k: one kernel replaces topk_partial + topk_merge (no cand buffer,
// one launch less, 34 MB less traffic). Block = (b, 64-col group); 256 thr
// as 4 row-quarters x 64 cols. Thread scans 256 rows of its column in the
// s = l*invT + LW[n] domain; per-col 4-way LDS merge; rq==0 finishes
// (sum-exp of top-16, fused aff_g) and writes out directly.
// Global top-16 is a subset of the union of per-quarter top-16s.
// ===========================================================================
__global__ __launch_bounds__(256) void topk_fused_kernel(
    const float* __restrict__ L, const float* __restrict__ pstat,
    float* __restrict__ out) {
  const int b = blockIdx.x;    // 0..63
  const int cg = blockIdx.y;   // 0..7
  const int tid = threadIdx.x; // 0..255
  const int rq = tid >> 6;     // row-quarter 0..3
  const int cl = tid & 63;
  const int c = cg * 64 + cl;

  __shared__ float sLW[1024];        // 4 KB
  __shared__ float sTop[3][64][16];  // 12 KB

  // Phase A: LW[n] = -(ln(sum_k pstat[n][k]) + invT) for all 1024 rows of b.
#pragma unroll
  for (int q = 0; q < 4; ++q) {
    const int r = tid * 4 + q;  // 0..1023
    const float* p = pstat + ((size_t)b * 1024 + r) * 8;
    float S = 0.f;
#pragma unroll
    for (int k = 0; k < 8; ++k) S += p[k];
    sLW[r] = -(__logf(S) + INV_TEMP);
  }
  __syncthreads();

  // Phase B: per-thread top-16 over its 256 rows (col c).
  float top[16];
#pragma unroll
  for (int j = 0; j < 16; ++j) top[j] = -3.0e38f;
  const float* Lp = L + ((size_t)b * 1024 + (size_t)rq * 256) * 512 + c;
  const int lwb = rq * 256;
#pragma unroll 1
  for (int n0 = 0; n0 < 256; n0 += 8) {
    float v[8];
#pragma unroll
    for (int u = 0; u < 8; ++u) v[u] = Lp[(size_t)(n0 + u) * 512];
#pragma unroll
    for (int u = 0; u < 8; ++u)
      insert16(top, fmaf(v[u], INV_TEMP, sLW[lwb + n0 + u]));
  }

  // Phase C: merge 4 quarters per column; finish.
  if (rq > 0) {
#pragma unroll
    for (int j = 0; j < 16; ++j) sTop[rq - 1][cl][j] = top[j];
  }
  __syncthreads();
  if (rq == 0) {
#pragma unroll
    for (int kb = 0; kb < 3; ++kb) {
      float v[16];
#pragma unroll
      for (int j = 0; j < 16; ++j) v[j] = sTop[kb][cl][j];
#pragma unroll
      for (int j = 0; j < 16; ++j) insert16(top, v[j]);
    }
    float se = 0.f;
#pragma unroll
    for (int j = 0; j < 16; ++j) se += __expf(top[j]);
    // aff_g from the cls logit row (row 65536+b) + its pstat.
    const float* pc = pstat + ((size_t)65536 + b) * 8;
    float S = 0.f;
#pragma unroll
    for (int k = 0; k < 8; ++k) S += pc[k];
    const float lg = L[((size_t)65536 + b) * 512 + c];
    const float ag = __expf(fmaf(lg, INV_TEMP, -(__logf(S) + INV_TEMP)));
    out[b * 512 + c] = GAMMA_ * ag + (1.0f - GAMMA_) * (se * (1.0f / 16.0f));
  }
}

// ===========================================================================
// OLD PATH (fallback if workspace too small for packed-A buffers).
// ===========================================================================

__global__ __launch_bounds__(256) void prep_kernel(
    const float* __restrict__ vcls, const float* __restrict__ text,
    unsigned short* __restrict__ Bh, unsigned short* __restrict__ Bl,
    float* __restrict__ Aext) {
  const int wid = blockIdx.x * 4 + (threadIdx.x >> 6);
  const int lane = threadIdx.x & 63;
  if (wid < 512) {
    const float* src = text + (size_t)wid * 512;
    const float4 v0 = ((const float4*)src)[lane];
    const float4 v1 = ((const float4*)src)[lane + 64];
    float ss = v0.x * v0.x + v0.y * v0.y + v0.z * v0.z + v0.w * v0.w +
               v1.x * v1.x + v1.y * v1.y + v1.z * v1.z + v1.w * v1.w;
#pragma unroll
    for (int off = 32; off; off >>= 1) ss += __shfl_xor(ss, off);
    const float scale = 1.0f / fmaxf(sqrtf(ss), 1e-12f);
    float a[8] = {v0.x * scale, v0.y * scale, v0.z * scale, v0.w * scale,
                  v1.x * scale, v1.y * scale, v1.z * scale, v1.w * scale};
    ushort4 h0, l0, h1, l1;
    h0.x = f2bf(a[0]); l0.x = f2bf(a[0] - bf2f(h0.x));
    h0.y = f2bf(a[1]); l0.y = f2bf(a[1] - bf2f(h0.y));
    h0.z = f2bf(a[2]); l0.z = f2bf(a[2] - bf2f(h0.z));
    h0.w = f2bf(a[3]); l0.w = f2bf(a[3] - bf2f(h0.w));
    h1.x = f2bf(a[4]); l1.x = f2bf(a[4] - bf2f(h1.x));
    h1.y = f2bf(a[5]); l1.y = f2bf(a[5] - bf2f(h1.y));
    h1.z = f2bf(a[6]); l1.z = f2bf(a[6] - bf2f(h1.z));
    h1.w = f2bf(a[7]); l1.w = f2bf(a[7] - bf2f(h1.w));
    ((ushort4*)(Bh + (size_t)wid * 512))[lane] = h0;
    ((ushort4*)(Bh + (size_t)wid * 512))[lane + 64] = h1;
    ((ushort4*)(Bl + (size_t)wid * 512))[lane] = l0;
    ((ushort4*)(Bl + (size_t)wid * 512))[lane + 64] = l1;
  } else {
    const int r = wid - 512;  // 0..127
    float4* dst = (float4*)(Aext + (size_t)r * 512);
    if (r < 64) {
      const float4* src = (const float4*)(vcls + (size_t)r * 512);
      dst[lane] = src[lane];
      dst[lane + 64] = src[lane + 64];
    } else {
      const float4 z = {0.f, 0.f, 0.f, 0.f};
      dst[lane] = z;
      dst[lane + 64] = z;
    }
  }
}

__global__ __launch_bounds__(256) void gemm_raw_kernel(
    const float* __restrict__ Apat, const float* __restrict__ Aext,
    const unsigned short* __restrict__ Bhi, const unsigned short* __restrict__ Blo,
    float* __restrict__ Cout, float* __restrict__ pstat) {
  __shared__ __align__(16) unsigned char smem[32768];
  float* sA = (float*)smem;                              // 128 x 32 fp32
  unsigned short* sBh = (unsigned short*)(smem + 16384); // 128 x 32 bf16
  unsigned short* sBl = (unsigned short*)(smem + 24576);
  const int tid = threadIdx.x;
  const int lane = tid & 63;
  const int w = tid >> 6;
  const int wm = w >> 1, wn = w & 1;

  const int L = blockIdx.x;  // 0..2051
  int bm, bn;
  if (L < 2048) {
    const int xcd = L & 7;
    const int slot = L >> 3;
    bn = slot & 3;
    bm = (slot >> 2) * 8 + xcd;
  } else {
    bm = 512;
    bn = L - 2048;
  }
  const float* Abase =
      (bm < 512) ? (Apat + (size_t)bm * 128 * 512) : Aext;

  unsigned aSrc[4];
#pragma unroll
  for (int q = 0; q < 4; ++q) {
    const int s = tid + q * 256;
    const int row = s >> 3, pos = s & 7;
    const int g = pos ^ (row & 7);
    aSrc[q] = (unsigned)row * 512u + (unsigned)g * 4u;
  }
  const int m0 = tid >> 2, g0 = (tid & 3) ^ ((m0 >> 1) & 3);
  const int i1 = 256 + tid;
  const int m1 = i1 >> 2, g1 = (i1 & 3) ^ ((m1 >> 1) & 3);
  const unsigned bO0 = (unsigned)(bn * 128 + m0) * 512u + (unsigned)g0 * 8u;
  const unsigned bO1 = (unsigned)(bn * 128 + m1) * 512u + (unsigned)g1 * 8u;

  const int l15 = lane & 15, kg = lane >> 4;
  int fA0[4], fA1[4], cB[4];
#pragma unroll
  for (int i = 0; i < 4; ++i) {
    const int ml = wm * 64 + i * 16 + l15;
    const int p0 = (2 * kg) ^ (ml & 7);
    const int p1 = (2 * kg + 1) ^ (ml & 7);
    fA0[i] = (ml * 8 + p0) * 4;
    fA1[i] = (ml * 8 + p1) * 4;
    const int nl = wn * 64 + i * 16 + l15;
    cB[i] = (nl * 4 + (kg ^ ((nl >> 1) & 3))) * 8;
  }

  floatx4 acc[4][4] = {};
  float ssq[4] = {0.f, 0.f, 0.f, 0.f};

  for (int ks = 0; ks < 16; ++ks) {
    const unsigned ko = (unsigned)ks * 32u;
#pragma unroll
    for (int q = 0; q < 4; ++q)
      GL16(Abase + aSrc[q] + ko, (unsigned short*)sA + (w * 512 + q * 2048));
    GL16(Bhi + bO0 + ko, sBh + (unsigned)tid * 8u);
    GL16(Bhi + bO1 + ko, sBh + 2048u + (unsigned)tid * 8u);
    GL16(Blo + bO0 + ko, sBl + (unsigned)tid * 8u);
    GL16(Blo + bO1 + ko, sBl + 2048u + (unsigned)tid * 8u);
    __syncthreads();

    short8 bh[4], bl[4];
#pragma unroll
    for (int j = 0; j < 4; ++j) {
      bh[j] = *(const short8*)(sBh + cB[j]);
      bl[j] = *(const short8*)(sBl + cB[j]);
    }
#pragma unroll
    for (int i = 0; i < 4; ++i) {
      const float4 x0 = *(const float4*)(sA + fA0[i]);
      const float4 x1 = *(const float4*)(sA + fA1[i]);
      const float xs[8] = {x0.x, x0.y, x0.z, x0.w, x1.x, x1.y, x1.z, x1.w};
      short8 ah, al;
#pragma unroll
      for (int e = 0; e < 8; ++e) {
        const float f = xs[e];
        ssq[i] = fmaf(f, f, ssq[i]);
        const unsigned u = __float_as_uint(f) + 0x8000u;
        ah[e] = (short)(u >> 16);
        const float hif = __uint_as_float(u & 0xFFFF0000u);
        al[e] = (short)(__float_as_uint(f - hif) >> 16);
      }
#pragma unroll
      for (int j = 0; j < 4; ++j) {
        acc[i][j] = __builtin_amdgcn_mfma_f32_16x16x32_bf16(ah, bh[j], acc[i][j], 0, 0, 0);
        acc[i][j] = __builtin_amdgcn_mfma_f32_16x16x32_bf16(ah, bl[j], acc[i][j], 0, 0, 0);
        acc[i][j] = __builtin_amdgcn_mfma_f32_16x16x32_bf16(al, bh[j], acc[i][j], 0, 0, 0);
      }
    }
    __syncthreads();
  }

  float inv[4];
#pragma unroll
  for (int i = 0; i < 4; ++i) {
    float s = ssq[i];
    s += __shfl_xor(s, 16);
    s += __shfl_xor(s, 32);
    inv[i] = 1.0f / fmaxf(sqrtf(s), 1e-12f);
  }

  const int quad = kg;
  const unsigned rowb0 = (unsigned)(bm * 128 + wm * 64 + quad * 4);
  const unsigned colb0 = (unsigned)(bn * 128 + wn * 64 + l15);
  const int pk = bn * 2 + wn;
#pragma unroll
  for (int i = 0; i < 4; ++i) {
    float iv[4];
#pragma unroll
    for (int r = 0; r < 4; ++r) iv[r] = __shfl(inv[i], quad * 20 + r);
    float sc[4][4];
#pragma unroll
    for (int j = 0; j < 4; ++j)
#pragma unroll
      for (int r = 0; r < 4; ++r) sc[j][r] = acc[i][j][r] * iv[r];
#pragma unroll
    for (int j = 0; j < 4; ++j) {
      const unsigned col = colb0 + j * 16;
#pragma unroll
      for (int r = 0; r < 4; ++r)
        Cout[(size_t)(rowb0 + i * 16 + r) * 512 + col] = sc[j][r];
    }
#pragma unroll
    for (int r = 0; r < 4; ++r) {
      float se = __expf((sc[0][r] - 1.0f) * INV_TEMP) +
                 __expf((sc[1][r] - 1.0f) * INV_TEMP) +
                 __expf((sc[2][r] - 1.0f) * INV_TEMP) +
                 __expf((sc[3][r] - 1.0f) * INV_TEMP);
      se += __shfl_xor(se, 1);
      se += __shfl_xor(se, 2);
      se += __shfl_xor(se, 4);
      se += __shfl_xor(se, 8);
      if (l15 == 0) pstat[(size_t)(rowb0 + i * 16 + r) * 8 + pk] = se;
    }
  }
}

// ---------------------------------------------------------------------------
extern "C" void kernel_launch(void* const* d_in, const int* in_sizes, int n_in,
                              void* d_out, int out_size, void* d_ws, size_t ws_size,
                              hipStream_t stream) {
  const float* vcls = (const float*)d_in[0];  // [64,512]
  const float* vpat = (const float*)d_in[1];  // [64,1024,512]
  const float* text = (const float*)d_in[2];  // [512,512]
  float* out = (float*)d_out;                 // [64,512]

  char* p = (char*)d_ws;
  auto carve = [&](size_t bytes) -> char* {
    char* r = p;
    p += (bytes + 255) & ~(size_t)255;
    return r;
  };

  // ---- New path (pack v3 + r1 GEMM + fused topk): ~272 MB workspace.
  {
    float* logits = (float*)carve((size_t)ROWS_NEW * 512 * 4);
    unsigned short* Bh = (unsigned short*)carve((size_t)512 * 512 * 2);
    unsigned short* Bl = (unsigned short*)carve((size_t)512 * 512 * 2);
    float* pstat = (float*)carve((size_t)ROWS_NEW * 8 * 4);
    unsigned short* Ah = (unsigned short*)carve((size_t)ROWS_NEW * 512 * 2);
    unsigned short* Al = (unsigned short*)carve((size_t)ROWS_NEW * 512 * 2);
    if ((size_t)(p - (char*)d_ws) <= ws_size) {
      pack_kernel<<<4144, 256, 0, stream>>>(vcls, vpat, text, Bh, Bl, Ah, Al);
      gemm_lean_kernel<<<2056, 256, 0, stream>>>(Ah, Al, Bh, Bl, logits, pstat);
      topk_fused_kernel<<<dim3(64, 8), 256, 0, stream>>>(logits, pstat, out);
      return;
    }
  }

  // ---- Fallback: raw-A pipeline (~138 MB workspace), fused topk.
  p = (char*)d_ws;
  float* logits = (float*)carve((size_t)ROWS_PAD * 512 * 4);
  unsigned short* Bh = (unsigned short*)carve((size_t)512 * 512 * 2);
  unsigned short* Bl = (unsigned short*)carve((size_t)512 * 512 * 2);
  float* pstat = (float*)carve((size_t)ROWS_PAD * 8 * 4);
  float* Aext = (float*)carve((size_t)128 * 512 * 4);
  if ((size_t)(p - (char*)d_ws) > ws_size) return;

  prep_kernel<<<160, 256, 0, stream>>>(vcls, text, Bh, Bl, Aext);
  gemm_raw_kernel<<<2052, 256, 0, stream>>>(vpat, Aext, Bh, Bl, logits, pstat);
  topk_fused_kernel<<<dim3(64, 8), 256, 0, stream>>>(logits, pstat, out);
}